// Round 3
// baseline (150.885 us; speedup 1.0000x reference)
//
#include <hip/hip_runtime.h>
#include <math.h>

#define N_NODES 50000
#define HEADS 4
#define NEG_SLOPE 0.2f
#define LN_EPS 1e-5f
#define SLOTS 80   // max stored in-degree; Poisson(16) tail @80 ~ 1e-30
#define GR 64      // gemm rows per block (4 waves x 16-row MFMA tiles)
#define EPB 2048   // edges per bin block (256 threads x 8)
#define DSH 8      // coarse bucket = dst >> 8
#define NB 196     // ceil(50000 / 256) buckets
#define CAP 40     // staging capacity per (bucket, block); Binom(2048,1/196) mean 10.4, P(>40)~1e-12
#define HBW 40     // hb row stride in dwords: 32 int8-h words + 8 rec words (160B)

typedef short short8 __attribute__((ext_vector_type(8)));
typedef float f32x4 __attribute__((ext_vector_type(4)));

// ---------- helpers ----------

__device__ __forceinline__ short f2bf(float f) {  // fp32 -> bf16 RNE
    unsigned u = __float_as_uint(f);
    return (short)((u + 0x7fffu + ((u >> 16) & 1u)) >> 16);
}

// per-block int64/int32 layout detect: wave 0 ballots high words of first 64 pairs
__device__ __forceinline__ int detect_is64(const int* __restrict__ ei, int t, int* s_flag) {
    if (t < 64) {
        int nz = (ei[2 * t + 1] != 0) ? 1 : 0;
        unsigned long long b = __ballot(nz);
        if (t == 0) *s_flag = (b == 0ULL) ? 1 : 0;
    }
    __syncthreads();
    return *s_flag;
}

// signed int8 at byte position p of u -> float
__device__ __forceinline__ float s8f(unsigned u, int p) {
    return (float)((int)(u << (24 - 8 * p)) >> 24);
}

// leaky-relu then exp
__device__ __forceinline__ float edge_w(float v) {
    v = v > 0.f ? v : NEG_SLOPE * v;
    return __expf(v);
}

// ---------- kernels ----------

// Heterogeneous kernel, roles interleaved 1 bin : 2 gemm by blockIdx%3.
// bin role: fully-coalesced uint4 edge loads (8 consecutive edges/thread),
// LDS-atomic coarse binning by dst>>8 into per-(bucket,block) staging cells.
// gemm role: bf16 MFMA (16x16x32), W^T staged once as bf16 into XOR-swizzled
// LDS. Epilogue writes int8 h AND the per-source softmax record
// {a_src[h],hscale} x4 into ONE 160B hb row (k2 edge gather = 3 lines, not 4).
__global__ __launch_bounds__(256, 4) void gemm_scatter_kernel(
    const float* __restrict__ x, const float* __restrict__ W,
    const float* __restrict__ att_src, const float* __restrict__ att_dst,
    unsigned* __restrict__ hb, float* __restrict__ a_dst,
    const int* __restrict__ ei, int E, int nScatter, int nGemm,
    unsigned* __restrict__ staging, int* __restrict__ scnt) {
    __shared__ __align__(16) char smem[40960];   // 32KB Wt + 4x2KB epilogue / bin lcnt
    const int t = threadIdx.x;
    const int b = (int)blockIdx.x;

    const bool isBin = (b % 3) == 0;
    const int rid = isBin ? (b / 3) : (2 * (b / 3) + (b % 3) - 1);

    if (isBin) {
        if (rid >= nScatter) return;
        int is64 = detect_is64(ei, t, (int*)smem);
        int* lcnt = (int*)smem + 64;             // after the is64 flag
        for (int i = t; i < NB; i += 256) lcnt[i] = 0;
        __syncthreads();

        const int e0 = rid * EPB + t * 8;        // 8 consecutive edges per thread
        int ss[8], dd[8];
        if (e0 + 8 <= E) {
            if (is64) {
                const uint4* ps4 = (const uint4*)(ei + 2 * (size_t)e0);
                const uint4* pd4 = (const uint4*)(ei + 2 * ((size_t)E + e0));
#pragma unroll
                for (int u = 0; u < 4; ++u) {
                    uint4 qs = ps4[u], qd = pd4[u];
                    ss[2 * u] = (int)qs.x; ss[2 * u + 1] = (int)qs.z;
                    dd[2 * u] = (int)qd.x; dd[2 * u + 1] = (int)qd.z;
                }
            } else {
                const uint4* ps4 = (const uint4*)(ei + e0);
                const uint4* pd4 = (const uint4*)(ei + (size_t)E + e0);
#pragma unroll
                for (int u = 0; u < 2; ++u) {
                    uint4 qs = ps4[u], qd = pd4[u];
                    ss[4 * u] = (int)qs.x; ss[4 * u + 1] = (int)qs.y;
                    ss[4 * u + 2] = (int)qs.z; ss[4 * u + 3] = (int)qs.w;
                    dd[4 * u] = (int)qd.x; dd[4 * u + 1] = (int)qd.y;
                    dd[4 * u + 2] = (int)qd.z; dd[4 * u + 3] = (int)qd.w;
                }
            }
        } else {
#pragma unroll
            for (int u = 0; u < 8; ++u) {
                int e = e0 + u;
                if (e < E) {
                    if (is64) { ss[u] = ei[2 * e]; dd[u] = ei[2 * (E + e)]; }
                    else      { ss[u] = ei[e];     dd[u] = ei[E + e]; }
                } else { ss[u] = -1; dd[u] = 0; }
            }
        }
#pragma unroll
        for (int u = 0; u < 8; ++u) {
            if (ss[u] < 0) continue;
            int bkt = dd[u] >> DSH;
            int p = atomicAdd(&lcnt[bkt], 1);    // LDS atomic
            if (p < CAP)
                staging[((size_t)bkt * nScatter + rid) * CAP + p] =
                    (unsigned)ss[u] | ((unsigned)dd[u] << 16);
        }
        __syncthreads();
        for (int i = t; i < NB; i += 256)
            scnt[(size_t)i * nScatter + rid] = min(lcnt[i], CAP);
        return;
    }

    // ---- gemm+att role ----
    if (rid >= nGemm) return;
    const int rowBase = rid * GR;
    const int l = t & 63;
    const int wv = t >> 6;

    // stage W^T as bf16 into LDS, rows n (128) x 16 units of 8 k (16B each),
    // unit XOR-swizzled by (n&7) so both the b128 writes here and the b128
    // fragment reads below are bank-conflict-free.
    {
        const int nlo = l & 7, khi = l >> 3;   // 8 cols x 8 k-units per wave-iter
        for (int i = 0; i < 8; ++i) {
            int tile = wv + 4 * i;             // 0..31
            int n = (tile & 15) * 8 + nlo;     // 0..127
            int k8 = (tile >> 4) * 8 + khi;    // 0..15
            short8 pk;
#pragma unroll
            for (int jj = 0; jj < 8; ++jj)
                pk[jj] = f2bf(W[(k8 * 8 + jj) * 128 + n]);
            int us = (k8 & 8) | ((k8 & 7) ^ (n & 7));
            *(short8*)(smem + n * 256 + us * 16) = pk;
        }
    }
    __syncthreads();

    const int g = l >> 4;   // k-subgroup 0..3 (8 k each)
    const int c = l & 15;   // A-row / B-col / D-col within tile

    f32x4 acc[8];
#pragma unroll
    for (int ct = 0; ct < 8; ++ct) acc[ct] = {0.f, 0.f, 0.f, 0.f};

    // k-loop: wave wv owns rows [rowBase+wv*16, +16), all 8 col-tiles
    {
        int arow = rowBase + wv * 16 + c;
        if (arow >= N_NODES) arow = N_NODES - 1;   // clamp loads; stores guarded
        const float* xrow = x + (size_t)arow * 128;
#pragma unroll
        for (int kk = 0; kk < 4; ++kk) {
            float4 xa = *(const float4*)(xrow + kk * 32 + g * 8);
            float4 xb = *(const float4*)(xrow + kk * 32 + g * 8 + 4);
            short8 af;
            af[0] = f2bf(xa.x); af[1] = f2bf(xa.y); af[2] = f2bf(xa.z); af[3] = f2bf(xa.w);
            af[4] = f2bf(xb.x); af[5] = f2bf(xb.y); af[6] = f2bf(xb.z); af[7] = f2bf(xb.w);
#pragma unroll
            for (int ct = 0; ct < 8; ++ct) {
                int n = ct * 16 + c;
                int u = kk * 4 + g;
                int us = (u & 8) | ((u & 7) ^ (n & 7));
                short8 bf = *(const short8*)(smem + n * 256 + us * 16);
                acc[ct] = __builtin_amdgcn_mfma_f32_16x16x32_bf16(af, bf, acc[ct], 0, 0, 0);
            }
        }
    }

    // epilogue: D layout col=lane&15, row=(lane>>4)*4+reg  (verified gfx950 map)
    char* ep = smem + 32768 + wv * 2048;   // per-wave 16x128 int8 transpose buf
    float asA[4], asB[4], adA[4], adB[4];
#pragma unroll
    for (int h = 0; h < 4; ++h) {
        asA[h] = att_src[h * 32 + c];
        asB[h] = att_src[h * 32 + 16 + c];
        adA[h] = att_dst[h * 32 + c];
        adB[h] = att_dst[h * 32 + 16 + c];
    }
#pragma unroll
    for (int r = 0; r < 4; ++r) {
        float v[8];
#pragma unroll
        for (int ct = 0; ct < 8; ++ct) v[ct] = acc[ct][r];

        // per-row absmax over 128 channels (8 regs x 16 lanes of this row)
        float m = fabsf(v[0]);
#pragma unroll
        for (int ct = 1; ct < 8; ++ct) m = fmaxf(m, fabsf(v[ct]));
#pragma unroll
        for (int o = 1; o < 16; o <<= 1) m = fmaxf(m, __shfl_xor(m, o, 64));
        m = fmaxf(m, 1e-20f);
        const float inv = 127.0f / m;

        // att projections: head h owns col-tiles 2h (ch c) and 2h+1 (ch c+16)
        float sp[4], dp[4];
#pragma unroll
        for (int h = 0; h < 4; ++h) {
            sp[h] = v[2 * h] * asA[h] + v[2 * h + 1] * asB[h];
            dp[h] = v[2 * h] * adA[h] + v[2 * h + 1] * adB[h];
        }
#pragma unroll
        for (int o = 1; o < 16; o <<= 1) {
#pragma unroll
            for (int h = 0; h < 4; ++h) {
                sp[h] += __shfl_xor(sp[h], o, 64);
                dp[h] += __shfl_xor(dp[h], o, 64);
            }
        }
        const int row_l = g * 4 + r;
        const int row = rowBase + wv * 16 + row_l;
        if (c == 0 && row < N_NODES) {
            const float hs = m * (1.0f / 127.0f);
            float4* rw = (float4*)(hb + (size_t)row * HBW + 32);
            rw[0] = make_float4(sp[0], hs, sp[1], hs);   // rec: {a_src[h], hscale} x4
            rw[1] = make_float4(sp[2], hs, sp[3], hs);
            a_dst[row * 4 + 0] = dp[0]; a_dst[row * 4 + 1] = dp[1];
            a_dst[row * 4 + 2] = dp[2]; a_dst[row * 4 + 3] = dp[3];
        }
#pragma unroll
        for (int ct = 0; ct < 8; ++ct) {
            int q = __float2int_rn(v[ct] * inv);
            ep[row_l * 128 + ct * 16 + c] = (char)q;
        }
    }

    // pack int8 tile -> hb words (word tx = channels 4tx..4tx+3), coalesced
#pragma unroll
    for (int w8 = 0; w8 < 8; ++w8) {
        int idx = w8 * 64 + l;
        int row_l = idx >> 5, tx = idx & 31;
        unsigned word = *(const unsigned*)(ep + row_l * 128 + tx * 4);
        int row = rowBase + wv * 16 + row_l;
        if (row < N_NODES) hb[(size_t)row * HBW + tx] = word;
    }
}

// Level 2: one block per coarse bucket (256 contiguous dsts). Gathers the
// bucket's staged edges (contiguous region), assigns slots via LDS atomics,
// stores esrc into the bucket's L2-resident 40KB window (full-line writebacks,
// no partial-line amp), and writes cnt[] directly (no memset needed).
__global__ __launch_bounds__(256) void build_kernel(
    const unsigned* __restrict__ staging, const int* __restrict__ scnt,
    int nScatter, int* __restrict__ cnt, unsigned short* __restrict__ esrc) {
    __shared__ int lcnt2[256];
    const int B = blockIdx.x;
    const int t = threadIdx.x;
    lcnt2[t] = 0;
    __syncthreads();

    for (int blk = t; blk < nScatter; blk += 256) {
        const int c = scnt[(size_t)B * nScatter + blk];   // coalesced across threads
        const unsigned* cell = staging + ((size_t)B * nScatter + blk) * CAP;
        for (int j = 0; j < c; j += 4) {
            uint4 q = *(const uint4*)(cell + j);          // CAP%4==0 -> in-bounds
            const int m = c - j;
            {
                int d = (int)(q.x >> 16);
                int p = atomicAdd(&lcnt2[d & 255], 1);
                if (p < SLOTS) esrc[(size_t)d * SLOTS + p] = (unsigned short)(q.x & 0xffffu);
            }
            if (m > 1) {
                int d = (int)(q.y >> 16);
                int p = atomicAdd(&lcnt2[d & 255], 1);
                if (p < SLOTS) esrc[(size_t)d * SLOTS + p] = (unsigned short)(q.y & 0xffffu);
            }
            if (m > 2) {
                int d = (int)(q.z >> 16);
                int p = atomicAdd(&lcnt2[d & 255], 1);
                if (p < SLOTS) esrc[(size_t)d * SLOTS + p] = (unsigned short)(q.z & 0xffffu);
            }
            if (m > 3) {
                int d = (int)(q.w >> 16);
                int p = atomicAdd(&lcnt2[d & 255], 1);
                if (p < SLOTS) esrc[(size_t)d * SLOTS + p] = (unsigned short)(q.w & 0xffffu);
            }
        }
    }
    __syncthreads();
    const int d = (B << DSH) + t;
    if (d < N_NODES) cnt[d] = lcnt2[t];
}

// 4 nodes per wave, 16 lanes per node, 8 channels (one uint2 of int8) per lane.
// Lane j of group g: node n = blk*16 + wave*4 + g, head hh = j>>2. hb rows are
// 160B: 128B int8 h + 4x{a_src[h],hscale} f32 pairs -- one edge gather touches
// a single contiguous 160B region (3 cache lines vs 4 with separate arrays).
// Softmax denom replicated within each 4-lane head subgroup. No max-sub:
// logits O(10), fp32 exp safe to 88, softmax shift-invariant.
__global__ __launch_bounds__(256) void gat_fused_kernel(
    const int* __restrict__ cnt, const unsigned short* __restrict__ esrc,
    const float* __restrict__ a_dst,
    const unsigned* __restrict__ hb,
    const float* __restrict__ bias, const float* __restrict__ x,
    const float* __restrict__ gamma, const float* __restrict__ beta,
    float* __restrict__ out) {
    const int t = threadIdx.x;
    const int l = t & 63;
    const int wv = t >> 6;
    const int g = l >> 4;
    const int j = l & 15;
    const int n = blockIdx.x * 16 + wv * 4 + g;
    const int hh = j >> 2;

    const uint2* hb2 = (const uint2*)hb;   // h row s: uint2[s*20 + j]; rec pair: [s*20+16+hh]

    const float adst_me = a_dst[(n << 2) + hh];
    uint2 rS = hb2[(unsigned)(n * 20 + 16 + hh)];
    float ps = edge_w(__uint_as_float(rS.x) + adst_me);

    uint2 hvS = hb2[(unsigned)(n * 20 + j)];
    {
        const float uS = ps * __uint_as_float(rS.y);
        float acc0 = uS * s8f(hvS.x, 0), acc1 = uS * s8f(hvS.x, 1);
        float acc2 = uS * s8f(hvS.x, 2), acc3 = uS * s8f(hvS.x, 3);
        float acc4 = uS * s8f(hvS.y, 0), acc5 = uS * s8f(hvS.y, 1);
        float acc6 = uS * s8f(hvS.y, 2), acc7 = uS * s8f(hvS.y, 3);

        const int deg = min(cnt[n], SLOTS);
        const unsigned short* row = esrc + n * SLOTS;

        for (int base = 0; base < deg; base += 8) {
            const int rem = deg - base;                 // >= 1
            uint4 q = *(const uint4*)(row + base);      // 8 u16 srcs, 16B-aligned
            int s0 = (int)(q.x & 0xffffu);
            int s1 = (rem > 1) ? (int)(q.x >> 16) : n;  // tail -> self row, w=0
            int s2 = (rem > 2) ? (int)(q.y & 0xffffu) : n;
            int s3 = (rem > 3) ? (int)(q.y >> 16) : n;
            int s4 = (rem > 4) ? (int)(q.z & 0xffffu) : n;
            int s5 = (rem > 5) ? (int)(q.z >> 16) : n;
            int s6 = (rem > 6) ? (int)(q.w & 0xffffu) : n;
            int s7 = (rem > 7) ? (int)(q.w >> 16) : n;

            uint2 r0 = hb2[(unsigned)(s0 * 20 + 16 + hh)];
            uint2 r1 = hb2[(unsigned)(s1 * 20 + 16 + hh)];
            uint2 r2 = hb2[(unsigned)(s2 * 20 + 16 + hh)];
            uint2 r3 = hb2[(unsigned)(s3 * 20 + 16 + hh)];
            uint2 r4 = hb2[(unsigned)(s4 * 20 + 16 + hh)];
            uint2 r5 = hb2[(unsigned)(s5 * 20 + 16 + hh)];
            uint2 r6 = hb2[(unsigned)(s6 * 20 + 16 + hh)];
            uint2 r7 = hb2[(unsigned)(s7 * 20 + 16 + hh)];
            uint2 h0 = hb2[(unsigned)(s0 * 20 + j)];
            uint2 h1 = hb2[(unsigned)(s1 * 20 + j)];
            uint2 h2 = hb2[(unsigned)(s2 * 20 + j)];
            uint2 h3 = hb2[(unsigned)(s3 * 20 + j)];
            uint2 h4 = hb2[(unsigned)(s4 * 20 + j)];
            uint2 h5 = hb2[(unsigned)(s5 * 20 + j)];
            uint2 h6 = hb2[(unsigned)(s6 * 20 + j)];
            uint2 h7 = hb2[(unsigned)(s7 * 20 + j)];

            float w0 = edge_w(__uint_as_float(r0.x) + adst_me);
            float w1 = (rem > 1) ? edge_w(__uint_as_float(r1.x) + adst_me) : 0.f;
            float w2 = (rem > 2) ? edge_w(__uint_as_float(r2.x) + adst_me) : 0.f;
            float w3 = (rem > 3) ? edge_w(__uint_as_float(r3.x) + adst_me) : 0.f;
            float w4 = (rem > 4) ? edge_w(__uint_as_float(r4.x) + adst_me) : 0.f;
            float w5 = (rem > 5) ? edge_w(__uint_as_float(r5.x) + adst_me) : 0.f;
            float w6 = (rem > 6) ? edge_w(__uint_as_float(r6.x) + adst_me) : 0.f;
            float w7 = (rem > 7) ? edge_w(__uint_as_float(r7.x) + adst_me) : 0.f;
            ps += (w0 + w1 + w2 + w3) + (w4 + w5 + w6 + w7);

            float u0 = w0 * __uint_as_float(r0.y), u1 = w1 * __uint_as_float(r1.y);
            float u2 = w2 * __uint_as_float(r2.y), u3 = w3 * __uint_as_float(r3.y);
            float u4 = w4 * __uint_as_float(r4.y), u5 = w5 * __uint_as_float(r5.y);
            float u6 = w6 * __uint_as_float(r6.y), u7 = w7 * __uint_as_float(r7.y);

            acc0 += u0 * s8f(h0.x, 0) + u1 * s8f(h1.x, 0) + u2 * s8f(h2.x, 0) + u3 * s8f(h3.x, 0)
                  + u4 * s8f(h4.x, 0) + u5 * s8f(h5.x, 0) + u6 * s8f(h6.x, 0) + u7 * s8f(h7.x, 0);
            acc1 += u0 * s8f(h0.x, 1) + u1 * s8f(h1.x, 1) + u2 * s8f(h2.x, 1) + u3 * s8f(h3.x, 1)
                  + u4 * s8f(h4.x, 1) + u5 * s8f(h5.x, 1) + u6 * s8f(h6.x, 1) + u7 * s8f(h7.x, 1);
            acc2 += u0 * s8f(h0.x, 2) + u1 * s8f(h1.x, 2) + u2 * s8f(h2.x, 2) + u3 * s8f(h3.x, 2)
                  + u4 * s8f(h4.x, 2) + u5 * s8f(h5.x, 2) + u6 * s8f(h6.x, 2) + u7 * s8f(h7.x, 2);
            acc3 += u0 * s8f(h0.x, 3) + u1 * s8f(h1.x, 3) + u2 * s8f(h2.x, 3) + u3 * s8f(h3.x, 3)
                  + u4 * s8f(h4.x, 3) + u5 * s8f(h5.x, 3) + u6 * s8f(h6.x, 3) + u7 * s8f(h7.x, 3);
            acc4 += u0 * s8f(h0.y, 0) + u1 * s8f(h1.y, 0) + u2 * s8f(h2.y, 0) + u3 * s8f(h3.y, 0)
                  + u4 * s8f(h4.y, 0) + u5 * s8f(h5.y, 0) + u6 * s8f(h6.y, 0) + u7 * s8f(h7.y, 0);
            acc5 += u0 * s8f(h0.y, 1) + u1 * s8f(h1.y, 1) + u2 * s8f(h2.y, 1) + u3 * s8f(h3.y, 1)
                  + u4 * s8f(h4.y, 1) + u5 * s8f(h5.y, 1) + u6 * s8f(h6.y, 1) + u7 * s8f(h7.y, 1);
            acc6 += u0 * s8f(h0.y, 2) + u1 * s8f(h1.y, 2) + u2 * s8f(h2.y, 2) + u3 * s8f(h3.y, 2)
                  + u4 * s8f(h4.y, 2) + u5 * s8f(h5.y, 2) + u6 * s8f(h6.y, 2) + u7 * s8f(h7.y, 2);
            acc7 += u0 * s8f(h0.y, 3) + u1 * s8f(h1.y, 3) + u2 * s8f(h2.y, 3) + u3 * s8f(h3.y, 3)
                  + u4 * s8f(h4.y, 3) + u5 * s8f(h5.y, 3) + u6 * s8f(h6.y, 3) + u7 * s8f(h7.y, 3);
        }

        const float inv = 1.0f / ps;   // denom replicated within head subgroup
        const float4* bias4 = (const float4*)bias;
        float4 bA = bias4[j * 2], bB = bias4[j * 2 + 1];
        float v0 = acc0 * inv + bA.x, v1 = acc1 * inv + bA.y;
        float v2 = acc2 * inv + bA.z, v3 = acc3 * inv + bA.w;
        float v4 = acc4 * inv + bB.x, v5 = acc5 * inv + bB.y;
        float v6 = acc6 * inv + bB.z, v7 = acc7 * inv + bB.w;

        // LayerNorm over 128 channels = 16 lanes of my group
        float s1 = v0 + v1 + v2 + v3 + v4 + v5 + v6 + v7;
        float s2 = v0 * v0 + v1 * v1 + v2 * v2 + v3 * v3 +
                   v4 * v4 + v5 * v5 + v6 * v6 + v7 * v7;
#pragma unroll
        for (int o = 1; o < 16; o <<= 1) {
            s1 += __shfl_xor(s1, o, 64);
            s2 += __shfl_xor(s2, o, 64);
        }
        float mu = s1 * (1.0f / 128.0f);
        float var = s2 * (1.0f / 128.0f) - mu * mu;
        float rstd = rsqrtf(var + LN_EPS);

        const float4* gamma4 = (const float4*)gamma;
        const float4* beta4 = (const float4*)beta;
        const float4* x4 = (const float4*)x;
        float4 gA = gamma4[j * 2], gB = gamma4[j * 2 + 1];
        float4 eA = beta4[j * 2], eB = beta4[j * 2 + 1];
        float4 xA = x4[(size_t)n * 32 + j * 2], xB = x4[(size_t)n * 32 + j * 2 + 1];

        float r0f = (v0 - mu) * rstd * gA.x + eA.x + xA.x;
        float r1f = (v1 - mu) * rstd * gA.y + eA.y + xA.y;
        float r2f = (v2 - mu) * rstd * gA.z + eA.z + xA.z;
        float r3f = (v3 - mu) * rstd * gA.w + eA.w + xA.w;
        float r4f = (v4 - mu) * rstd * gB.x + eB.x + xB.x;
        float r5f = (v5 - mu) * rstd * gB.y + eB.y + xB.y;
        float r6f = (v6 - mu) * rstd * gB.z + eB.z + xB.z;
        float r7f = (v7 - mu) * rstd * gB.w + eB.w + xB.w;

        const float k = 0.70710678118654752440f;
        float4 oA = make_float4(0.5f * r0f * (1.0f + erff(r0f * k)),
                                0.5f * r1f * (1.0f + erff(r1f * k)),
                                0.5f * r2f * (1.0f + erff(r2f * k)),
                                0.5f * r3f * (1.0f + erff(r3f * k)));
        float4 oB = make_float4(0.5f * r4f * (1.0f + erff(r4f * k)),
                                0.5f * r5f * (1.0f + erff(r5f * k)),
                                0.5f * r6f * (1.0f + erff(r6f * k)),
                                0.5f * r7f * (1.0f + erff(r7f * k)));
        float4* out4 = (float4*)out;
        out4[(size_t)n * 32 + j * 2] = oA;
        out4[(size_t)n * 32 + j * 2 + 1] = oB;
    }
}

// ---------- launch ----------

extern "C" void kernel_launch(void* const* d_in, const int* in_sizes, int n_in,
                              void* d_out, int out_size, void* d_ws, size_t ws_size,
                              hipStream_t stream) {
    const float* x       = (const float*)d_in[0];
    const int*   ei      = (const int*)d_in[1];
    const float* W       = (const float*)d_in[2];
    const float* att_src = (const float*)d_in[3];
    const float* att_dst = (const float*)d_in[4];
    const float* bias    = (const float*)d_in[5];
    const float* gamma   = (const float*)d_in[6];
    const float* beta    = (const float*)d_in[7];
    float* out = (float*)d_out;
    const int E = in_sizes[1] / 2;

    unsigned* hb         = (unsigned*)d_ws;                          // N*HBW (160B rows)
    float* a_dst         = (float*)(hb + (size_t)N_NODES * HBW);     // N*4
    int*   cnt           = (int*)(a_dst + N_NODES * 4);              // N
    unsigned short* esrc = (unsigned short*)(cnt + N_NODES);         // N*SLOTS u16

    const int nScatter = (E + EPB - 1) / EPB;               // 391 @ E=800k
    unsigned* staging    = (unsigned*)(esrc + (size_t)N_NODES * SLOTS);  // NB*nScatter*CAP
    int* scnt            = (int*)(staging + (size_t)NB * nScatter * CAP); // NB*nScatter

    const int nGemm = (N_NODES + GR - 1) / GR;              // 782
    int total = 3 * nScatter;                               // 1173
    const int needGemm = 3 * ((nGemm + 1) / 2);
    if (needGemm > total) total = needGemm;

    gemm_scatter_kernel<<<total, 256, 0, stream>>>(
        x, W, att_src, att_dst, hb, a_dst, ei, E, nScatter, nGemm,
        staging, scnt);
    build_kernel<<<NB, 256, 0, stream>>>(staging, scnt, nScatter, cnt, esrc);
    gat_fused_kernel<<<N_NODES / 16, 256, 0, stream>>>(cnt, esrc, a_dst, hb,
                                                       bias, x, gamma, beta, out);
}

// Round 4
// 145.546 us; speedup vs baseline: 1.0367x; 1.0367x over previous
//
#include <hip/hip_runtime.h>
#include <math.h>

#define N_NODES 50000
#define HEADS 4
#define NEG_SLOPE 0.2f
#define LN_EPS 1e-5f
#define SLOTS 80   // max stored in-degree; Poisson(16) tail @80 ~ 1e-30
#define GR 64      // gemm rows per block (4 waves x 16-row MFMA tiles)
#define EPB 2048   // edges per bin block (256 threads x 8)
#define DSH 8      // coarse bucket = dst >> 8
#define NB 196     // ceil(50000 / 256) buckets
#define CAP 40     // staging capacity per (block, bucket); Binom(2048,1/196) mean 10.4, P(>40)~1e-12

typedef short short8 __attribute__((ext_vector_type(8)));
typedef float f32x4 __attribute__((ext_vector_type(4)));

// ---------- helpers ----------

__device__ __forceinline__ short f2bf(float f) {  // fp32 -> bf16 RNE
    unsigned u = __float_as_uint(f);
    return (short)((u + 0x7fffu + ((u >> 16) & 1u)) >> 16);
}

// per-block int64/int32 layout detect: wave 0 ballots high words of first 64 pairs
__device__ __forceinline__ int detect_is64(const int* __restrict__ ei, int t, int* s_flag) {
    if (t < 64) {
        int nz = (ei[2 * t + 1] != 0) ? 1 : 0;
        unsigned long long b = __ballot(nz);
        if (t == 0) *s_flag = (b == 0ULL) ? 1 : 0;
    }
    __syncthreads();
    return *s_flag;
}

// signed int8 at byte position p of u -> float
__device__ __forceinline__ float s8f(unsigned u, int p) {
    return (float)((int)(u << (24 - 8 * p)) >> 24);
}

// leaky-relu then exp
__device__ __forceinline__ float edge_w(float v) {
    v = v > 0.f ? v : NEG_SLOPE * v;
    return __expf(v);
}

// ---------- kernels ----------

// Heterogeneous kernel, roles interleaved 1 bin : 2 gemm by blockIdx%3.
// bin role: coalesced uint4 edge loads -> LDS-atomic binning into LDS cells
// (196 buckets x CAP), then ONE dense coalesced 31KB flush to the block's
// private staging region ([block][bucket] layout -- no scattered global
// stores, no inter-block partial-line sharing).
// gemm role: bf16 MFMA (16x16x32), W^T staged once as bf16 into XOR-swizzled
// LDS. Epilogue: int8 h rows (128B ALIGNED = 1 cache line) + standalone
// rec[n][4]={a_src[h],hscale} (32B/node, 1.6MB L2-hot).
__global__ __launch_bounds__(256, 4) void gemm_scatter_kernel(
    const float* __restrict__ x, const float* __restrict__ W,
    const float* __restrict__ att_src, const float* __restrict__ att_dst,
    unsigned* __restrict__ hb, float* __restrict__ rec, float* __restrict__ a_dst,
    const int* __restrict__ ei, int E, int nScatter, int nGemm,
    unsigned* __restrict__ staging, int* __restrict__ scnt) {
    __shared__ __align__(16) char smem[40960];   // 32KB Wt + 4x2KB epilogue | bin: flag+lcnt+cells
    const int t = threadIdx.x;
    const int b = (int)blockIdx.x;

    const bool isBin = (b % 3) == 0;
    const int rid = isBin ? (b / 3) : (2 * (b / 3) + (b % 3) - 1);

    if (isBin) {
        if (rid >= nScatter) return;
        int is64 = detect_is64(ei, t, (int*)smem);
        int* lcnt = (int*)smem + 64;                     // 196 ints @ 256B
        unsigned* cells = (unsigned*)(smem + 1056);      // 196*CAP uints (31360B)
        for (int i = t; i < NB; i += 256) lcnt[i] = 0;
        __syncthreads();

        const int e0 = rid * EPB + t * 8;        // 8 consecutive edges per thread
        int ss[8], dd[8];
        if (e0 + 8 <= E) {
            if (is64) {
                const uint4* ps4 = (const uint4*)(ei + 2 * (size_t)e0);
                const uint4* pd4 = (const uint4*)(ei + 2 * ((size_t)E + e0));
#pragma unroll
                for (int u = 0; u < 4; ++u) {
                    uint4 qs = ps4[u], qd = pd4[u];
                    ss[2 * u] = (int)qs.x; ss[2 * u + 1] = (int)qs.z;
                    dd[2 * u] = (int)qd.x; dd[2 * u + 1] = (int)qd.z;
                }
            } else {
                const uint4* ps4 = (const uint4*)(ei + e0);
                const uint4* pd4 = (const uint4*)(ei + (size_t)E + e0);
#pragma unroll
                for (int u = 0; u < 2; ++u) {
                    uint4 qs = ps4[u], qd = pd4[u];
                    ss[4 * u] = (int)qs.x; ss[4 * u + 1] = (int)qs.y;
                    ss[4 * u + 2] = (int)qs.z; ss[4 * u + 3] = (int)qs.w;
                    dd[4 * u] = (int)qd.x; dd[4 * u + 1] = (int)qd.y;
                    dd[4 * u + 2] = (int)qd.z; dd[4 * u + 3] = (int)qd.w;
                }
            }
        } else {
#pragma unroll
            for (int u = 0; u < 8; ++u) {
                int e = e0 + u;
                if (e < E) {
                    if (is64) { ss[u] = ei[2 * e]; dd[u] = ei[2 * (E + e)]; }
                    else      { ss[u] = ei[e];     dd[u] = ei[E + e]; }
                } else { ss[u] = -1; dd[u] = 0; }
            }
        }
#pragma unroll
        for (int u = 0; u < 8; ++u) {
            if (ss[u] < 0) continue;
            int bkt = dd[u] >> DSH;
            int p = atomicAdd(&lcnt[bkt], 1);    // LDS atomic
            if (p < CAP)
                cells[bkt * CAP + p] = (unsigned)ss[u] | ((unsigned)dd[u] << 16);
        }
        __syncthreads();
        // dense coalesced flush of the block's private staging region
        uint4* dst4 = (uint4*)(staging + (size_t)rid * NB * CAP);
        const uint4* src4 = (const uint4*)cells;
        for (int i = t; i < NB * CAP / 4; i += 256) dst4[i] = src4[i];
        for (int i = t; i < NB; i += 256)
            scnt[(size_t)rid * NB + i] = min(lcnt[i], CAP);
        return;
    }

    // ---- gemm+att role ----
    if (rid >= nGemm) return;
    const int rowBase = rid * GR;
    const int l = t & 63;
    const int wv = t >> 6;

    // stage W^T as bf16 into LDS, rows n (128) x 16 units of 8 k (16B each),
    // unit XOR-swizzled by (n&7) so both the b128 writes here and the b128
    // fragment reads below are bank-conflict-free.
    {
        const int nlo = l & 7, khi = l >> 3;   // 8 cols x 8 k-units per wave-iter
        for (int i = 0; i < 8; ++i) {
            int tile = wv + 4 * i;             // 0..31
            int n = (tile & 15) * 8 + nlo;     // 0..127
            int k8 = (tile >> 4) * 8 + khi;    // 0..15
            short8 pk;
#pragma unroll
            for (int jj = 0; jj < 8; ++jj)
                pk[jj] = f2bf(W[(k8 * 8 + jj) * 128 + n]);
            int us = (k8 & 8) | ((k8 & 7) ^ (n & 7));
            *(short8*)(smem + n * 256 + us * 16) = pk;
        }
    }
    __syncthreads();

    const int g = l >> 4;   // k-subgroup 0..3 (8 k each)
    const int c = l & 15;   // A-row / B-col / D-col within tile

    f32x4 acc[8];
#pragma unroll
    for (int ct = 0; ct < 8; ++ct) acc[ct] = {0.f, 0.f, 0.f, 0.f};

    // k-loop: wave wv owns rows [rowBase+wv*16, +16), all 8 col-tiles
    {
        int arow = rowBase + wv * 16 + c;
        if (arow >= N_NODES) arow = N_NODES - 1;   // clamp loads; stores guarded
        const float* xrow = x + (size_t)arow * 128;
#pragma unroll
        for (int kk = 0; kk < 4; ++kk) {
            float4 xa = *(const float4*)(xrow + kk * 32 + g * 8);
            float4 xb = *(const float4*)(xrow + kk * 32 + g * 8 + 4);
            short8 af;
            af[0] = f2bf(xa.x); af[1] = f2bf(xa.y); af[2] = f2bf(xa.z); af[3] = f2bf(xa.w);
            af[4] = f2bf(xb.x); af[5] = f2bf(xb.y); af[6] = f2bf(xb.z); af[7] = f2bf(xb.w);
#pragma unroll
            for (int ct = 0; ct < 8; ++ct) {
                int n = ct * 16 + c;
                int u = kk * 4 + g;
                int us = (u & 8) | ((u & 7) ^ (n & 7));
                short8 bf = *(const short8*)(smem + n * 256 + us * 16);
                acc[ct] = __builtin_amdgcn_mfma_f32_16x16x32_bf16(af, bf, acc[ct], 0, 0, 0);
            }
        }
    }

    // epilogue: D layout col=lane&15, row=(lane>>4)*4+reg  (verified gfx950 map)
    char* ep = smem + 32768 + wv * 2048;   // per-wave 16x128 int8 transpose buf
    float asA[4], asB[4], adA[4], adB[4];
#pragma unroll
    for (int h = 0; h < 4; ++h) {
        asA[h] = att_src[h * 32 + c];
        asB[h] = att_src[h * 32 + 16 + c];
        adA[h] = att_dst[h * 32 + c];
        adB[h] = att_dst[h * 32 + 16 + c];
    }
#pragma unroll
    for (int r = 0; r < 4; ++r) {
        float v[8];
#pragma unroll
        for (int ct = 0; ct < 8; ++ct) v[ct] = acc[ct][r];

        // per-row absmax over 128 channels (8 regs x 16 lanes of this row)
        float m = fabsf(v[0]);
#pragma unroll
        for (int ct = 1; ct < 8; ++ct) m = fmaxf(m, fabsf(v[ct]));
#pragma unroll
        for (int o = 1; o < 16; o <<= 1) m = fmaxf(m, __shfl_xor(m, o, 64));
        m = fmaxf(m, 1e-20f);
        const float inv = 127.0f / m;

        // att projections: head h owns col-tiles 2h (ch c) and 2h+1 (ch c+16)
        float sp[4], dp[4];
#pragma unroll
        for (int h = 0; h < 4; ++h) {
            sp[h] = v[2 * h] * asA[h] + v[2 * h + 1] * asB[h];
            dp[h] = v[2 * h] * adA[h] + v[2 * h + 1] * adB[h];
        }
#pragma unroll
        for (int o = 1; o < 16; o <<= 1) {
#pragma unroll
            for (int h = 0; h < 4; ++h) {
                sp[h] += __shfl_xor(sp[h], o, 64);
                dp[h] += __shfl_xor(dp[h], o, 64);
            }
        }
        const int row_l = g * 4 + r;
        const int row = rowBase + wv * 16 + row_l;
        if (c == 0 && row < N_NODES) {
            const float hs = m * (1.0f / 127.0f);
            float4* rw = (float4*)(rec + (size_t)row * 8);
            rw[0] = make_float4(sp[0], hs, sp[1], hs);   // rec: {a_src[h], hscale} x4
            rw[1] = make_float4(sp[2], hs, sp[3], hs);
            a_dst[row * 4 + 0] = dp[0]; a_dst[row * 4 + 1] = dp[1];
            a_dst[row * 4 + 2] = dp[2]; a_dst[row * 4 + 3] = dp[3];
        }
#pragma unroll
        for (int ct = 0; ct < 8; ++ct) {
            int q = __float2int_rn(v[ct] * inv);
            ep[row_l * 128 + ct * 16 + c] = (char)q;
        }
    }

    // pack int8 tile -> hb words (word tx = channels 4tx..4tx+3), coalesced
#pragma unroll
    for (int w8 = 0; w8 < 8; ++w8) {
        int idx = w8 * 64 + l;
        int row_l = idx >> 5, tx = idx & 31;
        unsigned word = *(const unsigned*)(ep + row_l * 128 + tx * 4);
        int row = rowBase + wv * 16 + row_l;
        if (row < N_NODES) hb[(size_t)row * 32 + tx] = word;
    }
}

// Level 2: one block per coarse bucket (256 contiguous dsts). Gathers the
// bucket's staged cells (one 160B cell per bin block, [block][bucket] layout),
// assigns slots via LDS atomics, stores esrc into the bucket's L2-resident
// 40KB window, and writes cnt[] directly (no memset needed).
__global__ __launch_bounds__(256) void build_kernel(
    const unsigned* __restrict__ staging, const int* __restrict__ scnt,
    int nScatter, int* __restrict__ cnt, unsigned short* __restrict__ esrc) {
    __shared__ int lcnt2[256];
    const int B = blockIdx.x;
    const int t = threadIdx.x;
    lcnt2[t] = 0;
    __syncthreads();

    for (int blk = t; blk < nScatter; blk += 256) {
        const int c = scnt[(size_t)blk * NB + B];
        const unsigned* cell = staging + ((size_t)blk * NB + B) * CAP;
        for (int j = 0; j < c; j += 4) {
            uint4 q = *(const uint4*)(cell + j);          // CAP%4==0 -> in-bounds
            const int m = c - j;
            {
                int d = (int)(q.x >> 16);
                int p = atomicAdd(&lcnt2[d & 255], 1);
                if (p < SLOTS) esrc[(size_t)d * SLOTS + p] = (unsigned short)(q.x & 0xffffu);
            }
            if (m > 1) {
                int d = (int)(q.y >> 16);
                int p = atomicAdd(&lcnt2[d & 255], 1);
                if (p < SLOTS) esrc[(size_t)d * SLOTS + p] = (unsigned short)(q.y & 0xffffu);
            }
            if (m > 2) {
                int d = (int)(q.z >> 16);
                int p = atomicAdd(&lcnt2[d & 255], 1);
                if (p < SLOTS) esrc[(size_t)d * SLOTS + p] = (unsigned short)(q.z & 0xffffu);
            }
            if (m > 3) {
                int d = (int)(q.w >> 16);
                int p = atomicAdd(&lcnt2[d & 255], 1);
                if (p < SLOTS) esrc[(size_t)d * SLOTS + p] = (unsigned short)(q.w & 0xffffu);
            }
        }
    }
    __syncthreads();
    const int d = (B << DSH) + t;
    if (d < N_NODES) cnt[d] = lcnt2[t];
}

// 4 nodes per wave, 16 lanes per node, 8 channels (one uint2 of int8) per lane.
// Lane j of group g: node n = blk*16 + wave*4 + g, head hh = j>>2. h rows are
// 128B-ALIGNED int8 (exactly 1 cache line per edge gather); per-source softmax
// record rec[s][4]={a_src[h],hscale} is a 1.6MB L2-hot array, one uint2 load.
// Softmax denom replicated within each 4-lane head subgroup. No max-sub:
// logits O(10), fp32 exp safe to 88, softmax shift-invariant.
__global__ __launch_bounds__(256) void gat_fused_kernel(
    const int* __restrict__ cnt, const unsigned short* __restrict__ esrc,
    const float* __restrict__ rec, const float* __restrict__ a_dst,
    const unsigned* __restrict__ hb,
    const float* __restrict__ bias, const float* __restrict__ x,
    const float* __restrict__ gamma, const float* __restrict__ beta,
    float* __restrict__ out) {
    const int t = threadIdx.x;
    const int l = t & 63;
    const int wv = t >> 6;
    const int g = l >> 4;
    const int j = l & 15;
    const int n = blockIdx.x * 16 + wv * 4 + g;
    const int hh = j >> 2;

    const uint2* hb2 = (const uint2*)hb;     // h row s: uint2[s*16 + j]
    const uint2* rec2 = (const uint2*)rec;   // rec pair: [s*4 + hh]

    const float adst_me = a_dst[(n << 2) + hh];
    uint2 rS = rec2[(unsigned)(n * 4 + hh)];
    float ps = edge_w(__uint_as_float(rS.x) + adst_me);

    uint2 hvS = hb2[(unsigned)(n * 16 + j)];
    {
        const float uS = ps * __uint_as_float(rS.y);
        float acc0 = uS * s8f(hvS.x, 0), acc1 = uS * s8f(hvS.x, 1);
        float acc2 = uS * s8f(hvS.x, 2), acc3 = uS * s8f(hvS.x, 3);
        float acc4 = uS * s8f(hvS.y, 0), acc5 = uS * s8f(hvS.y, 1);
        float acc6 = uS * s8f(hvS.y, 2), acc7 = uS * s8f(hvS.y, 3);

        const int deg = min(cnt[n], SLOTS);
        const unsigned short* row = esrc + n * SLOTS;

        for (int base = 0; base < deg; base += 8) {
            const int rem = deg - base;                 // >= 1
            uint4 q = *(const uint4*)(row + base);      // 8 u16 srcs, 16B-aligned
            int s0 = (int)(q.x & 0xffffu);
            int s1 = (rem > 1) ? (int)(q.x >> 16) : n;  // tail -> self row, w=0
            int s2 = (rem > 2) ? (int)(q.y & 0xffffu) : n;
            int s3 = (rem > 3) ? (int)(q.y >> 16) : n;
            int s4 = (rem > 4) ? (int)(q.z & 0xffffu) : n;
            int s5 = (rem > 5) ? (int)(q.z >> 16) : n;
            int s6 = (rem > 6) ? (int)(q.w & 0xffffu) : n;
            int s7 = (rem > 7) ? (int)(q.w >> 16) : n;

            uint2 r0 = rec2[(unsigned)(s0 * 4 + hh)];
            uint2 r1 = rec2[(unsigned)(s1 * 4 + hh)];
            uint2 r2 = rec2[(unsigned)(s2 * 4 + hh)];
            uint2 r3 = rec2[(unsigned)(s3 * 4 + hh)];
            uint2 r4 = rec2[(unsigned)(s4 * 4 + hh)];
            uint2 r5 = rec2[(unsigned)(s5 * 4 + hh)];
            uint2 r6 = rec2[(unsigned)(s6 * 4 + hh)];
            uint2 r7 = rec2[(unsigned)(s7 * 4 + hh)];
            uint2 h0 = hb2[(unsigned)(s0 * 16 + j)];
            uint2 h1 = hb2[(unsigned)(s1 * 16 + j)];
            uint2 h2 = hb2[(unsigned)(s2 * 16 + j)];
            uint2 h3 = hb2[(unsigned)(s3 * 16 + j)];
            uint2 h4 = hb2[(unsigned)(s4 * 16 + j)];
            uint2 h5 = hb2[(unsigned)(s5 * 16 + j)];
            uint2 h6 = hb2[(unsigned)(s6 * 16 + j)];
            uint2 h7 = hb2[(unsigned)(s7 * 16 + j)];

            float w0 = edge_w(__uint_as_float(r0.x) + adst_me);
            float w1 = (rem > 1) ? edge_w(__uint_as_float(r1.x) + adst_me) : 0.f;
            float w2 = (rem > 2) ? edge_w(__uint_as_float(r2.x) + adst_me) : 0.f;
            float w3 = (rem > 3) ? edge_w(__uint_as_float(r3.x) + adst_me) : 0.f;
            float w4 = (rem > 4) ? edge_w(__uint_as_float(r4.x) + adst_me) : 0.f;
            float w5 = (rem > 5) ? edge_w(__uint_as_float(r5.x) + adst_me) : 0.f;
            float w6 = (rem > 6) ? edge_w(__uint_as_float(r6.x) + adst_me) : 0.f;
            float w7 = (rem > 7) ? edge_w(__uint_as_float(r7.x) + adst_me) : 0.f;
            ps += (w0 + w1 + w2 + w3) + (w4 + w5 + w6 + w7);

            float u0 = w0 * __uint_as_float(r0.y), u1 = w1 * __uint_as_float(r1.y);
            float u2 = w2 * __uint_as_float(r2.y), u3 = w3 * __uint_as_float(r3.y);
            float u4 = w4 * __uint_as_float(r4.y), u5 = w5 * __uint_as_float(r5.y);
            float u6 = w6 * __uint_as_float(r6.y), u7 = w7 * __uint_as_float(r7.y);

            acc0 += u0 * s8f(h0.x, 0) + u1 * s8f(h1.x, 0) + u2 * s8f(h2.x, 0) + u3 * s8f(h3.x, 0)
                  + u4 * s8f(h4.x, 0) + u5 * s8f(h5.x, 0) + u6 * s8f(h6.x, 0) + u7 * s8f(h7.x, 0);
            acc1 += u0 * s8f(h0.x, 1) + u1 * s8f(h1.x, 1) + u2 * s8f(h2.x, 1) + u3 * s8f(h3.x, 1)
                  + u4 * s8f(h4.x, 1) + u5 * s8f(h5.x, 1) + u6 * s8f(h6.x, 1) + u7 * s8f(h7.x, 1);
            acc2 += u0 * s8f(h0.x, 2) + u1 * s8f(h1.x, 2) + u2 * s8f(h2.x, 2) + u3 * s8f(h3.x, 2)
                  + u4 * s8f(h4.x, 2) + u5 * s8f(h5.x, 2) + u6 * s8f(h6.x, 2) + u7 * s8f(h7.x, 2);
            acc3 += u0 * s8f(h0.x, 3) + u1 * s8f(h1.x, 3) + u2 * s8f(h2.x, 3) + u3 * s8f(h3.x, 3)
                  + u4 * s8f(h4.x, 3) + u5 * s8f(h5.x, 3) + u6 * s8f(h6.x, 3) + u7 * s8f(h7.x, 3);
            acc4 += u0 * s8f(h0.y, 0) + u1 * s8f(h1.y, 0) + u2 * s8f(h2.y, 0) + u3 * s8f(h3.y, 0)
                  + u4 * s8f(h4.y, 0) + u5 * s8f(h5.y, 0) + u6 * s8f(h6.y, 0) + u7 * s8f(h7.y, 0);
            acc5 += u0 * s8f(h0.y, 1) + u1 * s8f(h1.y, 1) + u2 * s8f(h2.y, 1) + u3 * s8f(h3.y, 1)
                  + u4 * s8f(h4.y, 1) + u5 * s8f(h5.y, 1) + u6 * s8f(h6.y, 1) + u7 * s8f(h7.y, 1);
            acc6 += u0 * s8f(h0.y, 2) + u1 * s8f(h1.y, 2) + u2 * s8f(h2.y, 2) + u3 * s8f(h3.y, 2)
                  + u4 * s8f(h4.y, 2) + u5 * s8f(h5.y, 2) + u6 * s8f(h6.y, 2) + u7 * s8f(h7.y, 2);
            acc7 += u0 * s8f(h0.y, 3) + u1 * s8f(h1.y, 3) + u2 * s8f(h2.y, 3) + u3 * s8f(h3.y, 3)
                  + u4 * s8f(h4.y, 3) + u5 * s8f(h5.y, 3) + u6 * s8f(h6.y, 3) + u7 * s8f(h7.y, 3);
        }

        const float inv = 1.0f / ps;   // denom replicated within head subgroup
        const float4* bias4 = (const float4*)bias;
        float4 bA = bias4[j * 2], bB = bias4[j * 2 + 1];
        float v0 = acc0 * inv + bA.x, v1 = acc1 * inv + bA.y;
        float v2 = acc2 * inv + bA.z, v3 = acc3 * inv + bA.w;
        float v4 = acc4 * inv + bB.x, v5 = acc5 * inv + bB.y;
        float v6 = acc6 * inv + bB.z, v7 = acc7 * inv + bB.w;

        // LayerNorm over 128 channels = 16 lanes of my group
        float s1 = v0 + v1 + v2 + v3 + v4 + v5 + v6 + v7;
        float s2 = v0 * v0 + v1 * v1 + v2 * v2 + v3 * v3 +
                   v4 * v4 + v5 * v5 + v6 * v6 + v7 * v7;
#pragma unroll
        for (int o = 1; o < 16; o <<= 1) {
            s1 += __shfl_xor(s1, o, 64);
            s2 += __shfl_xor(s2, o, 64);
        }
        float mu = s1 * (1.0f / 128.0f);
        float var = s2 * (1.0f / 128.0f) - mu * mu;
        float rstd = rsqrtf(var + LN_EPS);

        const float4* gamma4 = (const float4*)gamma;
        const float4* beta4 = (const float4*)beta;
        const float4* x4 = (const float4*)x;
        float4 gA = gamma4[j * 2], gB = gamma4[j * 2 + 1];
        float4 eA = beta4[j * 2], eB = beta4[j * 2 + 1];
        float4 xA = x4[(size_t)n * 32 + j * 2], xB = x4[(size_t)n * 32 + j * 2 + 1];

        float r0f = (v0 - mu) * rstd * gA.x + eA.x + xA.x;
        float r1f = (v1 - mu) * rstd * gA.y + eA.y + xA.y;
        float r2f = (v2 - mu) * rstd * gA.z + eA.z + xA.z;
        float r3f = (v3 - mu) * rstd * gA.w + eA.w + xA.w;
        float r4f = (v4 - mu) * rstd * gB.x + eB.x + xB.x;
        float r5f = (v5 - mu) * rstd * gB.y + eB.y + xB.y;
        float r6f = (v6 - mu) * rstd * gB.z + eB.z + xB.z;
        float r7f = (v7 - mu) * rstd * gB.w + eB.w + xB.w;

        const float k = 0.70710678118654752440f;
        float4 oA = make_float4(0.5f * r0f * (1.0f + erff(r0f * k)),
                                0.5f * r1f * (1.0f + erff(r1f * k)),
                                0.5f * r2f * (1.0f + erff(r2f * k)),
                                0.5f * r3f * (1.0f + erff(r3f * k)));
        float4 oB = make_float4(0.5f * r4f * (1.0f + erff(r4f * k)),
                                0.5f * r5f * (1.0f + erff(r5f * k)),
                                0.5f * r6f * (1.0f + erff(r6f * k)),
                                0.5f * r7f * (1.0f + erff(r7f * k)));
        float4* out4 = (float4*)out;
        out4[(size_t)n * 32 + j * 2] = oA;
        out4[(size_t)n * 32 + j * 2 + 1] = oB;
    }
}

// ---------- launch ----------

extern "C" void kernel_launch(void* const* d_in, const int* in_sizes, int n_in,
                              void* d_out, int out_size, void* d_ws, size_t ws_size,
                              hipStream_t stream) {
    const float* x       = (const float*)d_in[0];
    const int*   ei      = (const int*)d_in[1];
    const float* W       = (const float*)d_in[2];
    const float* att_src = (const float*)d_in[3];
    const float* att_dst = (const float*)d_in[4];
    const float* bias    = (const float*)d_in[5];
    const float* gamma   = (const float*)d_in[6];
    const float* beta    = (const float*)d_in[7];
    float* out = (float*)d_out;
    const int E = in_sizes[1] / 2;

    unsigned* hb         = (unsigned*)d_ws;                          // N*32 uints (int8 h, 128B rows)
    float* rec           = (float*)(hb + (size_t)N_NODES * 32);      // N*8 ({a_src[h],hscale} x4)
    float* a_dst         = rec + (size_t)N_NODES * 8;                // N*4
    int*   cnt           = (int*)(a_dst + N_NODES * 4);              // N
    unsigned short* esrc = (unsigned short*)(cnt + N_NODES);         // N*SLOTS u16

    const int nScatter = (E + EPB - 1) / EPB;               // 391 @ E=800k
    unsigned* staging    = (unsigned*)(esrc + (size_t)N_NODES * SLOTS);   // nScatter*NB*CAP
    int* scnt            = (int*)(staging + (size_t)nScatter * NB * CAP); // nScatter*NB

    const int nGemm = (N_NODES + GR - 1) / GR;              // 782
    int total = 3 * nScatter;                               // 1173
    const int needGemm = 3 * ((nGemm + 1) / 2);
    if (needGemm > total) total = needGemm;

    gemm_scatter_kernel<<<total, 256, 0, stream>>>(
        x, W, att_src, att_dst, hb, rec, a_dst, ei, E, nScatter, nGemm,
        staging, scnt);
    build_kernel<<<NB, 256, 0, stream>>>(staging, scnt, nScatter, cnt, esrc);
    gat_fused_kernel<<<N_NODES / 16, 256, 0, stream>>>(cnt, esrc, rec, a_dst, hb,
                                                       bias, x, gamma, beta, out);
}